// Round 1
// baseline (401.331 us; speedup 1.0000x reference)
//
#include <hip/hip_runtime.h>
#include <math.h>

// Problem constants (match reference)
constexpr int CB  = 16;
constexpr int CN  = 1024;
constexpr int CD  = 512;
constexpr int CNH = 8;
constexpr int CHD = 64;     // head dim
constexpr int KM1 = 7;      // K_MAX + 1 candidate slots per batch
constexpr int ROWS = 16;    // rows per block in main kernel
constexpr int TPB = 256;

// ---------------------------------------------------------------------------
// Kernel A: compute K (scalar) from ego_speed / ego_distance
// ---------------------------------------------------------------------------
__global__ void k_computeK(const float* __restrict__ dist,
                           const float* __restrict__ speed,
                           int* __restrict__ Kout) {
    __shared__ int red[256];
    int t = threadIdx.x;
    int cnt = 0;
    for (int i = t; i < CB * CN; i += 256) cnt += (dist[i] < 20.0f) ? 1 : 0;
    red[t] = cnt;
    __syncthreads();
    for (int s = 128; s > 0; s >>= 1) {
        if (t < s) red[t] += red[t + s];
        __syncthreads();
    }
    if (t == 0) {
        float ss = 0.f;
        for (int i = 0; i < CB; i++) ss += speed[i];
        int K = 4;
        if (ss / (float)CB > 15.0f) K = (K + 1 > 6) ? 6 : K + 1;
        float density = (float)red[0] / (float)(CB * CN);
        if (density > 0.5f) K = (K + 1 > 6) ? 6 : K + 1;
        if (K > CN - 1) K = CN - 1;
        if (K < 0) K = 0;
        *Kout = K;
    }
}

// ---------------------------------------------------------------------------
// Kernel B: per-batch top-7 smallest distances (indices + values)
// ---------------------------------------------------------------------------
__global__ void k_top7(const float* __restrict__ dist,
                       int* __restrict__ candIdx,
                       float* __restrict__ candDist) {
    int b = blockIdx.x;
    int lane = threadIdx.x;  // 64 threads
    float d7[KM1];
    int   i7[KM1];
#pragma unroll
    for (int j = 0; j < KM1; j++) { d7[j] = 3.4e38f; i7[j] = -1; }
    for (int i = lane; i < CN; i += 64) {
        float d = dist[b * CN + i];
        if (d < d7[KM1 - 1]) {
            int p = KM1 - 1;
            while (p > 0 && d7[p - 1] > d) {
                d7[p] = d7[p - 1]; i7[p] = i7[p - 1]; p--;
            }
            d7[p] = d; i7[p] = i;
        }
    }
    __shared__ float sd[64 * KM1];
    __shared__ int   si[64 * KM1];
    for (int j = 0; j < KM1; j++) { sd[lane * KM1 + j] = d7[j]; si[lane * KM1 + j] = i7[j]; }
    __syncthreads();
    if (lane == 0) {
        float m7[KM1];
        int   mi[KM1];
        for (int j = 0; j < KM1; j++) { m7[j] = 3.4e38f; mi[j] = -1; }
        for (int e = 0; e < 64 * KM1; e++) {
            float d = sd[e];
            if (d < m7[KM1 - 1]) {
                int ii = si[e];
                int p = KM1 - 1;
                while (p > 0 && m7[p - 1] > d) {
                    m7[p] = m7[p - 1]; mi[p] = mi[p - 1]; p--;
                }
                m7[p] = d; mi[p] = ii;
            }
        }
        for (int j = 0; j < KM1; j++) {
            candIdx[b * KM1 + j]  = mi[j];
            candDist[b * KM1 + j] = m7[j];
        }
    }
}

// ---------------------------------------------------------------------------
// Kernel C: K/V projections of the 7 candidate rows per batch
// grid (CB, 4): each block handles 128 columns; threads 0..127 -> Kc, 128..255 -> Vc
// ---------------------------------------------------------------------------
__global__ void k_candkv(const float* __restrict__ X,
                         const float* __restrict__ Wk, const float* __restrict__ bk,
                         const float* __restrict__ Wv, const float* __restrict__ bv,
                         const int* __restrict__ candIdx,
                         float* __restrict__ Kc, float* __restrict__ Vc) {
    int b = blockIdx.x;
    int q = blockIdx.y;
    int t = threadIdx.x;
    __shared__ float xs[KM1][CD];
    for (int i = t; i < KM1 * CD; i += TPB) {
        int m = i / CD, k = i % CD;
        xs[m][k] = X[(size_t)(b * CN + candIdx[b * KM1 + m]) * CD + k];
    }
    __syncthreads();
    int c = q * 128 + (t & 127);
    const float* W    = (t < 128) ? Wk : Wv;
    const float* bias = (t < 128) ? bk : bv;
    float*       Out  = (t < 128) ? Kc : Vc;
    float acc[KM1];
#pragma unroll
    for (int m = 0; m < KM1; m++) acc[m] = bias[c];
    for (int k = 0; k < CD; k++) {
        float w = W[(size_t)k * CD + c];
#pragma unroll
        for (int m = 0; m < KM1; m++) acc[m] = fmaf(xs[m][k], w, acc[m]);
    }
#pragma unroll
    for (int m = 0; m < KM1; m++) Out[(size_t)(b * KM1 + m) * CD + c] = acc[m];
}

// ---------------------------------------------------------------------------
// Kernel D: fused main kernel. One block = 16 rows of one batch.
//   A: load X tile to LDS; build neighbor lists
//   B: Q GEMM (f32 register tiling): threads 0..127 do X@Wq, 128..255 do X@Weq
//   C: blend into LDS Q (overwrites X tile)
//   D: scores = (Q.K^T/8) * biasMLP; softmax over k
//   E: out = LayerNorm(X + attn@V)
// ---------------------------------------------------------------------------
__global__ __launch_bounds__(TPB) void k_main(
    const float* __restrict__ X, const float* __restrict__ dist,
    const float* __restrict__ mask,
    const float* __restrict__ Wq, const float* __restrict__ bq,
    const float* __restrict__ Weq, const float* __restrict__ beq,
    const float* __restrict__ Wd1, const float* __restrict__ bd1,
    const float* __restrict__ Wd2, const float* __restrict__ bd2,
    const float* __restrict__ lng, const float* __restrict__ lnb,
    const int* __restrict__ Kp, const int* __restrict__ candIdx,
    const float* __restrict__ candDist,
    const float* __restrict__ Kc, const float* __restrict__ Vc,
    float* __restrict__ out) {

    __shared__ __align__(16) float xq[ROWS][CD];   // X tile, later Q tile
    __shared__ float sw[ROWS][CNH][6];             // scores -> weights
    __shared__ int   snbr[ROWS][6];                // candidate SLOT per neighbor
    __shared__ float snbrd[ROWS][6];               // neighbor distance
    __shared__ float se[ROWS];                     // ego mask per row
    __shared__ float srd[ROWS];                    // q distance per row

    int b    = blockIdx.x / (CN / ROWS);
    int row0 = (blockIdx.x % (CN / ROWS)) * ROWS;
    int t    = threadIdx.x;
    int K    = *Kp;

    // ---- phase A
    {
        const float4* xg  = (const float4*)(X + (size_t)(b * CN + row0) * CD);
        float4*       xls = (float4*)xq;
        for (int i = t; i < ROWS * CD / 4; i += TPB) xls[i] = xg[i];
        if (t < ROWS) {
            se[t]  = mask[b * CN + row0 + t];
            srd[t] = dist[b * CN + row0 + t];
            int i = row0 + t, cnt = 0;
            for (int m = 0; m <= K && cnt < K; m++) {
                int c = candIdx[b * KM1 + m];
                if (c != i) {
                    snbr[t][cnt]  = m;
                    snbrd[t][cnt] = candDist[b * KM1 + m];
                    cnt++;
                }
            }
        }
    }
    __syncthreads();

    // ---- phase B: Q GEMM
    const float* W = (t < 128) ? Wq : Weq;
    int c0 = (t & 127) * 4;
    float acc[ROWS][4];
#pragma unroll
    for (int r = 0; r < ROWS; r++) {
        acc[r][0] = 0.f; acc[r][1] = 0.f; acc[r][2] = 0.f; acc[r][3] = 0.f;
    }
    for (int k = 0; k < CD; k += 4) {
        float4 w0 = *(const float4*)(W + (size_t)(k + 0) * CD + c0);
        float4 w1 = *(const float4*)(W + (size_t)(k + 1) * CD + c0);
        float4 w2 = *(const float4*)(W + (size_t)(k + 2) * CD + c0);
        float4 w3 = *(const float4*)(W + (size_t)(k + 3) * CD + c0);
#pragma unroll
        for (int r = 0; r < ROWS; r++) {
            float4 xv = *(const float4*)(&xq[r][k]);
            acc[r][0] = fmaf(xv.x, w0.x, fmaf(xv.y, w1.x, fmaf(xv.z, w2.x, fmaf(xv.w, w3.x, acc[r][0]))));
            acc[r][1] = fmaf(xv.x, w0.y, fmaf(xv.y, w1.y, fmaf(xv.z, w2.y, fmaf(xv.w, w3.y, acc[r][1]))));
            acc[r][2] = fmaf(xv.x, w0.z, fmaf(xv.y, w1.z, fmaf(xv.z, w2.z, fmaf(xv.w, w3.z, acc[r][2]))));
            acc[r][3] = fmaf(xv.x, w0.w, fmaf(xv.y, w1.w, fmaf(xv.z, w2.w, fmaf(xv.w, w3.w, acc[r][3]))));
        }
    }
    __syncthreads();   // all GEMM LDS reads done; xq can be overwritten

    // ---- phase C: blend Q into LDS (Q = (1-e)(XWq+bq) + e(XWeq+beq))
    if (t < 128) {
#pragma unroll
        for (int r = 0; r < ROWS; r++) {
            float e = se[r], oe = 1.f - e;
            xq[r][c0 + 0] = oe * (acc[r][0] + bq[c0 + 0]);
            xq[r][c0 + 1] = oe * (acc[r][1] + bq[c0 + 1]);
            xq[r][c0 + 2] = oe * (acc[r][2] + bq[c0 + 2]);
            xq[r][c0 + 3] = oe * (acc[r][3] + bq[c0 + 3]);
        }
    }
    __syncthreads();
    if (t >= 128) {
#pragma unroll
        for (int r = 0; r < ROWS; r++) {
            float e = se[r];
            xq[r][c0 + 0] += e * (acc[r][0] + beq[c0 + 0]);
            xq[r][c0 + 1] += e * (acc[r][1] + beq[c0 + 1]);
            xq[r][c0 + 2] += e * (acc[r][2] + beq[c0 + 2]);
            xq[r][c0 + 3] += e * (acc[r][3] + beq[c0 + 3]);
        }
    }
    __syncthreads();

    // ---- phase D: scores * bias, then softmax over k
    {
        int r = t >> 4, tr = t & 15;
        int np = CNH * K;
        for (int pi = tr; pi < np; pi += 16) {
            int h = pi & 7, k = pi >> 3;
            int m = snbr[r][k];
            float kd = snbrd[r][k];
            const float* kcrow = Kc + (size_t)(b * KM1 + m) * CD + h * CHD;
            const float* qrow  = &xq[r][h * CHD];
            float s = 0.f;
#pragma unroll 8
            for (int d = 0; d < CHD; d++) s = fmaf(qrow[d], kcrow[d], s);
            s *= 0.125f;  // 1/sqrt(64)
            float qd = srd[r];
            float bacc = bd2[h];
            for (int j = 0; j < 128; j++) {
                float hid = fmaf(qd, Wd1[j], fmaf(kd, Wd1[128 + j], bd1[j]));
                hid = fmaxf(hid, 0.f);
                bacc = fmaf(hid, Wd2[j * 8 + h], bacc);
            }
            sw[r][h][k] = s * bacc;
        }
    }
    __syncthreads();
    if (t < ROWS * CNH) {
        int r = t >> 3, h = t & 7;
        float mx = -3.4e38f;
        for (int k = 0; k < K; k++) mx = fmaxf(mx, sw[r][h][k]);
        float sum = 0.f;
        for (int k = 0; k < K; k++) {
            float w = expf(sw[r][h][k] - mx);
            sw[r][h][k] = w;
            sum += w;
        }
        float inv = 1.f / sum;
        for (int k = 0; k < K; k++) sw[r][h][k] *= inv;
    }
    __syncthreads();

    // ---- phase E: attn@V + residual + LayerNorm
    {
        int r = t >> 4, tr = t & 15;
        const float* xrow = X + (size_t)(b * CN + row0 + r) * CD;
        float vals[32];
        float sum = 0.f, sq = 0.f;
#pragma unroll
        for (int j = 0; j < 32; j++) {
            int d = j * 16 + tr;
            int h = d >> 6;
            float a = 0.f;
            for (int k = 0; k < K; k++) {
                int m = snbr[r][k];
                a = fmaf(sw[r][h][k], Vc[(size_t)(b * KM1 + m) * CD + d], a);
            }
            float v = xrow[d] + a;
            vals[j] = v;
            sum += v;
            sq = fmaf(v, v, sq);
        }
        for (int off = 8; off > 0; off >>= 1) {
            sum += __shfl_xor(sum, off, 16);
            sq  += __shfl_xor(sq,  off, 16);
        }
        float mu  = sum * (1.f / 512.f);
        float var = sq * (1.f / 512.f) - mu * mu;
        float inv = rsqrtf(var + 1e-5f);
        float* orow = out + (size_t)(b * CN + row0 + r) * CD;
#pragma unroll
        for (int j = 0; j < 32; j++) {
            int d = j * 16 + tr;
            orow[d] = (vals[j] - mu) * inv * lng[d] + lnb[d];
        }
    }
}

// ---------------------------------------------------------------------------
extern "C" void kernel_launch(void* const* d_in, const int* in_sizes, int n_in,
                              void* d_out, int out_size, void* d_ws, size_t ws_size,
                              hipStream_t stream) {
    (void)in_sizes; (void)n_in; (void)out_size; (void)ws_size;
    const float* X     = (const float*)d_in[0];
    const float* dist  = (const float*)d_in[1];
    const float* mask  = (const float*)d_in[2];
    const float* speed = (const float*)d_in[3];
    const float* Wq    = (const float*)d_in[4];
    const float* bq    = (const float*)d_in[5];
    const float* Wk    = (const float*)d_in[6];
    const float* bk    = (const float*)d_in[7];
    const float* Wv    = (const float*)d_in[8];
    const float* bv    = (const float*)d_in[9];
    const float* Weq   = (const float*)d_in[10];
    const float* beq   = (const float*)d_in[11];
    const float* Wd1   = (const float*)d_in[16];
    const float* bd1   = (const float*)d_in[17];
    const float* Wd2   = (const float*)d_in[18];
    const float* bd2   = (const float*)d_in[19];
    const float* lng   = (const float*)d_in[20];
    const float* lnb   = (const float*)d_in[21];
    float* out = (float*)d_out;

    char* ws = (char*)d_ws;
    int*   Kp       = (int*)(ws + 0);
    int*   candIdx  = (int*)(ws + 64);
    float* candDist = (float*)(ws + 512);
    float* Kc       = (float*)(ws + 1024);
    float* Vc       = (float*)(ws + 1024 + (size_t)CB * KM1 * CD * 4);

    k_computeK<<<1, 256, 0, stream>>>(dist, speed, Kp);
    k_top7<<<CB, 64, 0, stream>>>(dist, candIdx, candDist);
    k_candkv<<<dim3(CB, 4), TPB, 0, stream>>>(X, Wk, bk, Wv, bv, candIdx, Kc, Vc);
    k_main<<<CB * (CN / ROWS), TPB, 0, stream>>>(
        X, dist, mask, Wq, bq, Weq, beq, Wd1, bd1, Wd2, bd2, lng, lnb,
        Kp, candIdx, candDist, Kc, Vc, out);
}

// Round 2
// 309.990 us; speedup vs baseline: 1.2947x; 1.2947x over previous
//
#include <hip/hip_runtime.h>
#include <math.h>

constexpr int CB  = 16;
constexpr int CN  = 1024;
constexpr int CD  = 512;
constexpr int KM1 = 7;      // K_MAX + 1 candidate slots per batch

typedef __attribute__((ext_vector_type(8))) short bf8;
typedef __attribute__((ext_vector_type(4))) float f32x4;
typedef __attribute__((ext_vector_type(4))) unsigned short us4;

__device__ inline float bf2f(unsigned short u) {
    union { unsigned int i; float f; } v; v.i = ((unsigned)u) << 16; return v.f;
}
__device__ inline unsigned short f2bf(float f) {
    union { unsigned int i; float f; } v; v.f = f;
    unsigned r = v.i + 0x7FFFu + ((v.i >> 16) & 1u);
    return (unsigned short)(r >> 16);
}

// ---------------------------------------------------------------------------
// Kernel A: compute K (scalar) from ego_speed / ego_distance
// ---------------------------------------------------------------------------
__global__ void k_computeK(const float* __restrict__ dist,
                           const float* __restrict__ speed,
                           int* __restrict__ Kout) {
    __shared__ int red[256];
    int t = threadIdx.x;
    int cnt = 0;
    for (int i = t; i < CB * CN; i += 256) cnt += (dist[i] < 20.0f) ? 1 : 0;
    red[t] = cnt;
    __syncthreads();
    for (int s = 128; s > 0; s >>= 1) {
        if (t < s) red[t] += red[t + s];
        __syncthreads();
    }
    if (t == 0) {
        float ss = 0.f;
        for (int i = 0; i < CB; i++) ss += speed[i];
        int K = 4;
        if (ss / (float)CB > 15.0f) K = (K + 1 > 6) ? 6 : K + 1;
        float density = (float)red[0] / (float)(CB * CN);
        if (density > 0.5f) K = (K + 1 > 6) ? 6 : K + 1;
        if (K > CN - 1) K = CN - 1;
        if (K < 0) K = 0;
        *Kout = K;
    }
}

// ---------------------------------------------------------------------------
// Kernel B: per-batch top-7 smallest distances (indices + values)
// ---------------------------------------------------------------------------
__global__ void k_top7(const float* __restrict__ dist,
                       int* __restrict__ candIdx,
                       float* __restrict__ candDist) {
    int b = blockIdx.x;
    int lane = threadIdx.x;  // 64 threads
    float d7[KM1];
    int   i7[KM1];
#pragma unroll
    for (int j = 0; j < KM1; j++) { d7[j] = 3.4e38f; i7[j] = -1; }
    for (int i = lane; i < CN; i += 64) {
        float d = dist[b * CN + i];
        if (d < d7[KM1 - 1]) {
            int p = KM1 - 1;
            while (p > 0 && d7[p - 1] > d) {
                d7[p] = d7[p - 1]; i7[p] = i7[p - 1]; p--;
            }
            d7[p] = d; i7[p] = i;
        }
    }
    __shared__ float sd[64 * KM1];
    __shared__ int   si[64 * KM1];
    for (int j = 0; j < KM1; j++) { sd[lane * KM1 + j] = d7[j]; si[lane * KM1 + j] = i7[j]; }
    __syncthreads();
    if (lane == 0) {
        float m7[KM1];
        int   mi[KM1];
        for (int j = 0; j < KM1; j++) { m7[j] = 3.4e38f; mi[j] = -1; }
        for (int e = 0; e < 64 * KM1; e++) {
            float d = sd[e];
            if (d < m7[KM1 - 1]) {
                int ii = si[e];
                int p = KM1 - 1;
                while (p > 0 && m7[p - 1] > d) {
                    m7[p] = m7[p - 1]; mi[p] = mi[p - 1]; p--;
                }
                m7[p] = d; mi[p] = ii;
            }
        }
        for (int j = 0; j < KM1; j++) {
            candIdx[b * KM1 + j]  = mi[j];
            candDist[b * KM1 + j] = m7[j];
        }
    }
}

// ---------------------------------------------------------------------------
// Kernel C: K/V projections of the 7 candidate rows per batch
// ---------------------------------------------------------------------------
__global__ void k_candkv(const float* __restrict__ X,
                         const float* __restrict__ Wk, const float* __restrict__ bk,
                         const float* __restrict__ Wv, const float* __restrict__ bv,
                         const int* __restrict__ candIdx,
                         float* __restrict__ Kc, float* __restrict__ Vc) {
    int b = blockIdx.x;
    int q = blockIdx.y;
    int t = threadIdx.x;
    __shared__ float xs[KM1][CD];
    for (int i = t; i < KM1 * CD; i += 256) {
        int m = i / CD, k = i % CD;
        xs[m][k] = X[(size_t)(b * CN + candIdx[b * KM1 + m]) * CD + k];
    }
    __syncthreads();
    int c = q * 128 + (t & 127);
    const float* W    = (t < 128) ? Wk : Wv;
    const float* bias = (t < 128) ? bk : bv;
    float*       Out  = (t < 128) ? Kc : Vc;
    float acc[KM1];
#pragma unroll
    for (int m = 0; m < KM1; m++) acc[m] = bias[c];
#pragma unroll 8
    for (int k = 0; k < CD; k++) {
        float w = W[(size_t)k * CD + c];
#pragma unroll
        for (int m = 0; m < KM1; m++) acc[m] = fmaf(xs[m][k], w, acc[m]);
    }
#pragma unroll
    for (int m = 0; m < KM1; m++) Out[(size_t)(b * KM1 + m) * CD + c] = acc[m];
}

// ---------------------------------------------------------------------------
// Kernel Y: per (batch, head, mat): Y[b][mat*56 + m*8 + h][k] = sum_{c in head} W[k][c]*Kc[b][m][c]
// Also S0[b][mat][m][h] = sum_{c in head} bias[c]*Kc[b][m][c]
// ---------------------------------------------------------------------------
__global__ __launch_bounds__(64) void k_Y(
    const float* __restrict__ Wq, const float* __restrict__ bq,
    const float* __restrict__ Weq, const float* __restrict__ beq,
    const float* __restrict__ Kc, float* __restrict__ S0,
    unsigned short* __restrict__ Y) {
    int b = blockIdx.x, h = blockIdx.y, mat = blockIdx.z;
    const float* W    = mat ? Weq : Wq;
    const float* bias = mat ? beq : bq;
    __shared__ float sK[KM1][64];
    int t = threadIdx.x;
#pragma unroll
    for (int m = 0; m < KM1; m++) sK[m][t] = Kc[((size_t)(b * KM1 + m)) * CD + h * 64 + t];
    __syncthreads();
    float bv = bias[h * 64 + t];
#pragma unroll
    for (int m = 0; m < KM1; m++) {
        float p = bv * sK[m][t];
        for (int off = 32; off; off >>= 1) p += __shfl_xor(p, off);
        if (t == 0) S0[((b * 2 + mat) * KM1 + m) * 8 + h] = p;
    }
#pragma unroll
    for (int j = 0; j < 8; j++) {
        int k = j * 64 + t;
        const float* wrow = W + (size_t)k * CD + h * 64;
        float acc[KM1];
#pragma unroll
        for (int m = 0; m < KM1; m++) acc[m] = 0.f;
#pragma unroll
        for (int c4 = 0; c4 < 16; c4++) {
            float4 wv = *(const float4*)(wrow + c4 * 4);
#pragma unroll
            for (int m = 0; m < KM1; m++) {
                float4 kv = *(const float4*)&sK[m][c4 * 4];
                acc[m] = fmaf(wv.x, kv.x, fmaf(wv.y, kv.y, fmaf(wv.z, kv.z, fmaf(wv.w, kv.w, acc[m]))));
            }
        }
#pragma unroll
        for (int m = 0; m < KM1; m++)
            Y[((size_t)(b * 112) + mat * 56 + m * 8 + h) * 512 + k] = f2bf(acc[m]);
    }
}

// ---------------------------------------------------------------------------
// Kernel attn: fused scores (MFMA vs Y) + bias MLP + softmax + PV + residual + LN
// Block = 32 rows of one batch; 256 threads; grid = 16*32 = 512.
// ---------------------------------------------------------------------------
__global__ __launch_bounds__(256) void k_attn(
    const float* __restrict__ X, const float* __restrict__ dist,
    const float* __restrict__ mask,
    const float* __restrict__ Wd1, const float* __restrict__ bd1,
    const float* __restrict__ Wd2, const float* __restrict__ bd2,
    const float* __restrict__ lng, const float* __restrict__ lnb,
    const int* __restrict__ Kp, const int* __restrict__ candIdx,
    const float* __restrict__ candDist,
    const float* __restrict__ Vc, const float* __restrict__ S0,
    const unsigned short* __restrict__ Y,
    float* __restrict__ out) {

    __shared__ unsigned short sX[32][520];     // X tile bf16 (padded: 1040B rows, 16B-aligned)
    __shared__ float sS[32][116];              // raw scores vs all 7 cand x 8 h x 2 mats (112 cols)
    __shared__ unsigned short sVc[KM1][520];   // V rows bf16
    __shared__ float sW[32][8][6];             // biased scores -> softmax weights
    __shared__ float sBias[32][6][2][8];       // bias MLP partials (2 halves of hidden dim)
    __shared__ int   snbr[32][6];
    __shared__ float skd[32][6];
    __shared__ float srd[32];
    __shared__ float sE[32];
    __shared__ float sS0[112];

    int t = threadIdx.x;
    int b = blockIdx.x >> 5, rblk = blockIdx.x & 31;
    int row0 = b * CN + rblk * 32;   // global flat row
    int K = *Kp;

    // ---- phase A: staging
    for (int idx = t; idx < 32 * 128; idx += 256) {
        int r = idx >> 7, c4 = idx & 127;
        float4 xv = *(const float4*)(X + (size_t)(row0 + r) * CD + c4 * 4);
        us4 o; o.x = f2bf(xv.x); o.y = f2bf(xv.y); o.z = f2bf(xv.z); o.w = f2bf(xv.w);
        *(us4*)&sX[r][c4 * 4] = o;
    }
    for (int idx = t; idx < KM1 * 128; idx += 256) {
        int m = idx >> 7, c4 = idx & 127;
        float4 vv = *(const float4*)(Vc + ((size_t)(b * KM1 + m)) * CD + c4 * 4);
        us4 o; o.x = f2bf(vv.x); o.y = f2bf(vv.y); o.z = f2bf(vv.z); o.w = f2bf(vv.w);
        *(us4*)&sVc[m][c4 * 4] = o;
    }
    if (t < 112) sS0[t] = S0[b * 112 + t];
    if (t < 32) {
        int i = rblk * 32 + t;
        sE[t]  = mask[b * CN + i];
        srd[t] = dist[b * CN + i];
        int cnt = 0;
        for (int m = 0; m <= K && cnt < K; m++) {
            int c = candIdx[b * KM1 + m];
            if (c != i) { snbr[t][cnt] = m; skd[t][cnt] = candDist[b * KM1 + m]; cnt++; }
        }
    }
    __syncthreads();

    // ---- phase B1: score MFMA  S[r][n] = X_r . Y_n  (K=512)
    {
        int w = t >> 6, lane = t & 63, lr = lane & 15, kg = lane >> 4;
        f32x4 acc00 = {0.f, 0.f, 0.f, 0.f}, acc10 = acc00, acc01 = acc00, acc11 = acc00;
        bool has2 = (w < 3);
        const unsigned short* Yb = Y + (size_t)b * 112 * 512;
        const unsigned short* y0p = Yb + (size_t)(w * 16 + lr) * 512 + kg * 8;
        const unsigned short* y1p = Yb + (size_t)((w + 4) * 16 + lr) * 512 + kg * 8;
#pragma unroll
        for (int s = 0; s < 16; s++) {
            int k0 = s * 32 + kg * 8;
            bf8 a0 = *(const bf8*)&sX[lr][k0];
            bf8 a1 = *(const bf8*)&sX[16 + lr][k0];
            bf8 b0 = *(const bf8*)&y0p[s * 32];
            acc00 = __builtin_amdgcn_mfma_f32_16x16x32_bf16(a0, b0, acc00, 0, 0, 0);
            acc10 = __builtin_amdgcn_mfma_f32_16x16x32_bf16(a1, b0, acc10, 0, 0, 0);
            if (has2) {
                bf8 b1 = *(const bf8*)&y1p[s * 32];
                acc01 = __builtin_amdgcn_mfma_f32_16x16x32_bf16(a0, b1, acc01, 0, 0, 0);
                acc11 = __builtin_amdgcn_mfma_f32_16x16x32_bf16(a1, b1, acc11, 0, 0, 0);
            }
        }
        int n0 = w * 16 + lr;
#pragma unroll
        for (int q = 0; q < 4; q++) {
            sS[kg * 4 + q][n0]      = acc00[q];
            sS[16 + kg * 4 + q][n0] = acc10[q];
        }
        if (has2) {
            int n1 = (w + 4) * 16 + lr;
#pragma unroll
            for (int q = 0; q < 4; q++) {
                sS[kg * 4 + q][n1]      = acc01[q];
                sS[16 + kg * 4 + q][n1] = acc11[q];
            }
        }
    }
    // ---- phase B2: bias MLP (2 threads per (r,k) pair, split hidden dim)
    {
        int half = t & 1;
        int j0 = half * 64;
        for (int pid = t >> 1; pid < 32 * K; pid += 128) {
            int r = pid / K, k = pid - r * K;
            float qd = srd[r], kd = skd[r][k];
            float bacc[8];
#pragma unroll
            for (int h = 0; h < 8; h++) bacc[h] = 0.f;
            for (int j = j0; j < j0 + 64; j++) {
                float hid = fmaf(qd, Wd1[j], fmaf(kd, Wd1[128 + j], bd1[j]));
                hid = fmaxf(hid, 0.f);
                float4 wa = *(const float4*)(Wd2 + j * 8);
                float4 wb = *(const float4*)(Wd2 + j * 8 + 4);
                bacc[0] = fmaf(hid, wa.x, bacc[0]);
                bacc[1] = fmaf(hid, wa.y, bacc[1]);
                bacc[2] = fmaf(hid, wa.z, bacc[2]);
                bacc[3] = fmaf(hid, wa.w, bacc[3]);
                bacc[4] = fmaf(hid, wb.x, bacc[4]);
                bacc[5] = fmaf(hid, wb.y, bacc[5]);
                bacc[6] = fmaf(hid, wb.z, bacc[6]);
                bacc[7] = fmaf(hid, wb.w, bacc[7]);
            }
#pragma unroll
            for (int h = 0; h < 8; h++) sBias[r][k][half][h] = bacc[h];
        }
    }
    __syncthreads();

    // ---- phase C: blend ego/non-ego scores, multiply bias
    {
        int tot = 32 * 8 * K;
        for (int id = t; id < tot; id += 256) {
            int k = id % K; int rh = id / K; int r = rh >> 3, h = rh & 7;
            int m = snbr[r][k];
            float e = sE[r];
            float scq = sS[r][m * 8 + h]      + sS0[m * 8 + h];
            float sce = sS[r][56 + m * 8 + h] + sS0[56 + m * 8 + h];
            float sc = (1.f - e) * scq + e * sce;
            float bias = sBias[r][k][0][h] + sBias[r][k][1][h] + bd2[h];
            sW[r][h][k] = sc * 0.125f * bias;
        }
    }
    __syncthreads();

    // ---- phase D: softmax over k (256 tasks exactly)
    {
        int r = t >> 3, h = t & 7;
        float mx = -3.4e38f;
        for (int k = 0; k < K; k++) mx = fmaxf(mx, sW[r][h][k]);
        float sum = 0.f;
        for (int k = 0; k < K; k++) {
            float w0 = __expf(sW[r][h][k] - mx);
            sW[r][h][k] = w0;
            sum += w0;
        }
        float inv = 1.f / sum;
        for (int k = 0; k < K; k++) sW[r][h][k] *= inv;
    }
    __syncthreads();

    // ---- phase E: PV + residual + LayerNorm (8 threads per row)
    {
        int r = t >> 3, tr = t & 7;
        const float* xrow = X + (size_t)(row0 + r) * CD;
        float4 vals[16];
        float sum = 0.f, sq = 0.f;
#pragma unroll
        for (int j = 0; j < 16; j++) {
            int d = tr * 4 + j * 32;
            int h = j >> 1;
            float ax = 0.f, ay = 0.f, az = 0.f, aw = 0.f;
            for (int k = 0; k < K; k++) {
                int m = snbr[r][k];
                float wgt = sW[r][h][k];
                us4 vv = *(const us4*)&sVc[m][d];
                ax = fmaf(wgt, bf2f(vv.x), ax);
                ay = fmaf(wgt, bf2f(vv.y), ay);
                az = fmaf(wgt, bf2f(vv.z), az);
                aw = fmaf(wgt, bf2f(vv.w), aw);
            }
            float4 xv = *(const float4*)(xrow + d);
            float4 v;
            v.x = xv.x + ax; v.y = xv.y + ay; v.z = xv.z + az; v.w = xv.w + aw;
            vals[j] = v;
            sum += v.x + v.y + v.z + v.w;
            sq = fmaf(v.x, v.x, sq); sq = fmaf(v.y, v.y, sq);
            sq = fmaf(v.z, v.z, sq); sq = fmaf(v.w, v.w, sq);
        }
        sum += __shfl_xor(sum, 1); sq += __shfl_xor(sq, 1);
        sum += __shfl_xor(sum, 2); sq += __shfl_xor(sq, 2);
        sum += __shfl_xor(sum, 4); sq += __shfl_xor(sq, 4);
        float mu  = sum * (1.f / 512.f);
        float var = sq * (1.f / 512.f) - mu * mu;
        float inv = rsqrtf(var + 1e-5f);
        float* orow = out + (size_t)(row0 + r) * CD;
#pragma unroll
        for (int j = 0; j < 16; j++) {
            int d = tr * 4 + j * 32;
            float4 g  = *(const float4*)(lng + d);
            float4 bb = *(const float4*)(lnb + d);
            float4 v = vals[j];
            float4 o;
            o.x = (v.x - mu) * inv * g.x + bb.x;
            o.y = (v.y - mu) * inv * g.y + bb.y;
            o.z = (v.z - mu) * inv * g.z + bb.z;
            o.w = (v.w - mu) * inv * g.w + bb.w;
            *(float4*)(orow + d) = o;
        }
    }
}

// ---------------------------------------------------------------------------
extern "C" void kernel_launch(void* const* d_in, const int* in_sizes, int n_in,
                              void* d_out, int out_size, void* d_ws, size_t ws_size,
                              hipStream_t stream) {
    (void)in_sizes; (void)n_in; (void)out_size; (void)ws_size;
    const float* X     = (const float*)d_in[0];
    const float* dist  = (const float*)d_in[1];
    const float* mask  = (const float*)d_in[2];
    const float* speed = (const float*)d_in[3];
    const float* Wq    = (const float*)d_in[4];
    const float* bq    = (const float*)d_in[5];
    const float* Wk    = (const float*)d_in[6];
    const float* bk    = (const float*)d_in[7];
    const float* Wv    = (const float*)d_in[8];
    const float* bv    = (const float*)d_in[9];
    const float* Weq   = (const float*)d_in[10];
    const float* beq   = (const float*)d_in[11];
    const float* Wd1   = (const float*)d_in[16];
    const float* bd1   = (const float*)d_in[17];
    const float* Wd2   = (const float*)d_in[18];
    const float* bd2   = (const float*)d_in[19];
    const float* lng   = (const float*)d_in[20];
    const float* lnb   = (const float*)d_in[21];
    float* out = (float*)d_out;

    char* ws = (char*)d_ws;
    int*   Kp       = (int*)(ws);
    int*   candIdx  = (int*)(ws + 256);
    float* candDist = (float*)(ws + 1024);
    float* S0       = (float*)(ws + 2048);                 // 16*2*7*8*4 = 7168 B
    float* Kc       = (float*)(ws + 16384);                // 229376 B
    float* Vc       = (float*)(ws + 245760);               // 229376 B
    unsigned short* Y = (unsigned short*)(ws + 475136);    // 16*112*512*2 = 1835008 B

    k_computeK<<<1, 256, 0, stream>>>(dist, speed, Kp);
    k_top7<<<CB, 64, 0, stream>>>(dist, candIdx, candDist);
    k_candkv<<<dim3(CB, 4), 256, 0, stream>>>(X, Wk, bk, Wv, bv, candIdx, Kc, Vc);
    k_Y<<<dim3(CB, 8, 2), 64, 0, stream>>>(Wq, bq, Weq, beq, Kc, S0, Y);
    k_attn<<<CB * 32, 256, 0, stream>>>(X, dist, mask, Wd1, bd1, Wd2, bd2, lng, lnb,
                                        Kp, candIdx, candDist, Vc, S0, Y, out);
}

// Round 3
// 183.713 us; speedup vs baseline: 2.1846x; 1.6874x over previous
//
#include <hip/hip_runtime.h>
#include <math.h>

constexpr int CB  = 16;
constexpr int CN  = 1024;
constexpr int CD  = 512;
constexpr int KM1 = 7;      // K_MAX + 1 candidate slots per batch

typedef __attribute__((ext_vector_type(8))) short bf8;
typedef __attribute__((ext_vector_type(4))) float f32x4;
typedef __attribute__((ext_vector_type(4))) unsigned short us4;

__device__ inline float bf2f(unsigned short u) {
    union { unsigned int i; float f; } v; v.i = ((unsigned)u) << 16; return v.f;
}
__device__ inline unsigned short f2bf(float f) {
    union { unsigned int i; float f; } v; v.f = f;
    unsigned r = v.i + 0x7FFFu + ((v.i >> 16) & 1u);
    return (unsigned short)(r >> 16);
}
__device__ inline bf8 pack8(float4 x, float4 y) {
    bf8 r;
    r[0] = (short)f2bf(x.x); r[1] = (short)f2bf(x.y);
    r[2] = (short)f2bf(x.z); r[3] = (short)f2bf(x.w);
    r[4] = (short)f2bf(y.x); r[5] = (short)f2bf(y.y);
    r[6] = (short)f2bf(y.z); r[7] = (short)f2bf(y.w);
    return r;
}

// ---------------------------------------------------------------------------
// Kernel A: compute K (scalar) from ego_speed / ego_distance
// ---------------------------------------------------------------------------
__global__ void k_computeK(const float* __restrict__ dist,
                           const float* __restrict__ speed,
                           int* __restrict__ Kout) {
    __shared__ int red[256];
    int t = threadIdx.x;
    int cnt = 0;
    for (int i = t; i < CB * CN; i += 256) cnt += (dist[i] < 20.0f) ? 1 : 0;
    red[t] = cnt;
    __syncthreads();
    for (int s = 128; s > 0; s >>= 1) {
        if (t < s) red[t] += red[t + s];
        __syncthreads();
    }
    if (t == 0) {
        float ss = 0.f;
        for (int i = 0; i < CB; i++) ss += speed[i];
        int K = 4;
        if (ss / (float)CB > 15.0f) K = (K + 1 > 6) ? 6 : K + 1;
        float density = (float)red[0] / (float)(CB * CN);
        if (density > 0.5f) K = (K + 1 > 6) ? 6 : K + 1;
        if (K > CN - 1) K = CN - 1;
        if (K < 0) K = 0;
        *Kout = K;
    }
}

// ---------------------------------------------------------------------------
// Kernel B: per-batch top-7 smallest distances (indices + values)
// ---------------------------------------------------------------------------
__global__ void k_top7(const float* __restrict__ dist,
                       int* __restrict__ candIdx,
                       float* __restrict__ candDist) {
    int b = blockIdx.x;
    int lane = threadIdx.x;  // 64 threads
    float d7[KM1];
    int   i7[KM1];
#pragma unroll
    for (int j = 0; j < KM1; j++) { d7[j] = 3.4e38f; i7[j] = -1; }
    for (int i = lane; i < CN; i += 64) {
        float d = dist[b * CN + i];
        if (d < d7[KM1 - 1]) {
            int p = KM1 - 1;
            while (p > 0 && d7[p - 1] > d) {
                d7[p] = d7[p - 1]; i7[p] = i7[p - 1]; p--;
            }
            d7[p] = d; i7[p] = i;
        }
    }
    __shared__ float sd[64 * KM1];
    __shared__ int   si[64 * KM1];
    for (int j = 0; j < KM1; j++) { sd[lane * KM1 + j] = d7[j]; si[lane * KM1 + j] = i7[j]; }
    __syncthreads();
    if (lane == 0) {
        float m7[KM1];
        int   mi[KM1];
        for (int j = 0; j < KM1; j++) { m7[j] = 3.4e38f; mi[j] = -1; }
        for (int e = 0; e < 64 * KM1; e++) {
            float d = sd[e];
            if (d < m7[KM1 - 1]) {
                int ii = si[e];
                int p = KM1 - 1;
                while (p > 0 && m7[p - 1] > d) {
                    m7[p] = m7[p - 1]; mi[p] = mi[p - 1]; p--;
                }
                m7[p] = d; mi[p] = ii;
            }
        }
        for (int j = 0; j < KM1; j++) {
            candIdx[b * KM1 + j]  = mi[j];
            candDist[b * KM1 + j] = m7[j];
        }
    }
}

// ---------------------------------------------------------------------------
// Kernel C: K/V projections of the 7 candidate rows per batch
// ---------------------------------------------------------------------------
__global__ void k_candkv(const float* __restrict__ X,
                         const float* __restrict__ Wk, const float* __restrict__ bk,
                         const float* __restrict__ Wv, const float* __restrict__ bv,
                         const int* __restrict__ candIdx,
                         float* __restrict__ Kc, float* __restrict__ Vc) {
    int b = blockIdx.x;
    int q = blockIdx.y;
    int t = threadIdx.x;
    __shared__ float xs[KM1][CD];
    for (int i = t; i < KM1 * CD; i += 256) {
        int m = i / CD, k = i % CD;
        xs[m][k] = X[(size_t)(b * CN + candIdx[b * KM1 + m]) * CD + k];
    }
    __syncthreads();
    int c = q * 128 + (t & 127);
    const float* W    = (t < 128) ? Wk : Wv;
    const float* bias = (t < 128) ? bk : bv;
    float*       Out  = (t < 128) ? Kc : Vc;
    float acc[KM1];
#pragma unroll
    for (int m = 0; m < KM1; m++) acc[m] = bias[c];
#pragma unroll 8
    for (int k = 0; k < CD; k++) {
        float w = W[(size_t)k * CD + c];
#pragma unroll
        for (int m = 0; m < KM1; m++) acc[m] = fmaf(xs[m][k], w, acc[m]);
    }
#pragma unroll
    for (int m = 0; m < KM1; m++) Out[(size_t)(b * KM1 + m) * CD + c] = acc[m];
}

// ---------------------------------------------------------------------------
// Kernel Y (MFMA rewrite): per block (b,h,half):
//   Y[b][mat*56 + m*8 + h][k] = sum_{c in head h} W[k][c] * Kc[b][m][c]
//   via 16x16x32 bf16 MFMA: A = Kc head-slice [7(pad16) x 64], B^T = W rows.
//   S0[b][mat][m][h] = sum_{c in head} bias[c]*Kc[b][m][c]  (half==0 only)
// ---------------------------------------------------------------------------
__global__ __launch_bounds__(256) void k_Y(
    const float* __restrict__ Wq, const float* __restrict__ bq,
    const float* __restrict__ Weq, const float* __restrict__ beq,
    const float* __restrict__ Kc, float* __restrict__ S0,
    unsigned short* __restrict__ Y) {
    int b = blockIdx.x >> 3, h = blockIdx.x & 7;
    int half = blockIdx.y;
    __shared__ unsigned short sA[16][64];
    __shared__ float sKf[KM1][64];
    int t = threadIdx.x;
    for (int i = t; i < 16 * 64; i += 256) {
        int m = i >> 6, c = i & 63;
        float v = (m < KM1) ? Kc[((size_t)(b * KM1 + m)) * CD + h * 64 + c] : 0.f;
        sA[m][c] = f2bf(v);
        if (m < KM1) sKf[m][c] = v;
    }
    __syncthreads();
    if (half == 0 && t < 14) {
        int mat = t / 7, m = t % 7;
        const float* bias = mat ? beq : bq;
        float s = 0.f;
        for (int c = 0; c < 64; c++) s = fmaf(bias[h * 64 + c], sKf[m][c], s);
        S0[((b * 2 + mat) * KM1 + m) * 8 + h] = s;
    }
    int w = t >> 6, lane = t & 63, lr = lane & 15, kg = lane >> 4;
    bf8 a0 = *(const bf8*)&sA[lr][kg * 8];
    bf8 a1 = *(const bf8*)&sA[lr][32 + kg * 8];
#pragma unroll
    for (int mat = 0; mat < 2; mat++) {
        const float* W = mat ? Weq : Wq;
        unsigned short* Yb = Y + ((size_t)(b * 112) + mat * 56) * 512;
#pragma unroll
        for (int nt = 0; nt < 4; nt++) {
            int n0 = (half * 16 + w * 4 + nt) * 16;   // k_out tile base
            const float* wp = W + (size_t)(n0 + lr) * CD + h * 64 + kg * 8;
            float4 f0 = *(const float4*)(wp);
            float4 f1 = *(const float4*)(wp + 4);
            float4 f2 = *(const float4*)(wp + 32);
            float4 f3 = *(const float4*)(wp + 36);
            f32x4 acc = {0.f, 0.f, 0.f, 0.f};
            acc = __builtin_amdgcn_mfma_f32_16x16x32_bf16(a0, pack8(f0, f1), acc, 0, 0, 0);
            acc = __builtin_amdgcn_mfma_f32_16x16x32_bf16(a1, pack8(f2, f3), acc, 0, 0, 0);
            int k_out = n0 + lr;
#pragma unroll
            for (int q = 0; q < 4; q++) {
                int m = kg * 4 + q;   // A row
                if (m < KM1)
                    Yb[(size_t)(m * 8 + h) * 512 + k_out] = f2bf(acc[q]);
            }
        }
    }
}

// ---------------------------------------------------------------------------
// Kernel attn: fused scores (MFMA vs Y) + bias MLP + softmax + PV + residual + LN
// Block = 32 rows of one batch; 256 threads; grid = 16*32 = 512.
// ---------------------------------------------------------------------------
__global__ __launch_bounds__(256) void k_attn(
    const float* __restrict__ X, const float* __restrict__ dist,
    const float* __restrict__ mask,
    const float* __restrict__ Wd1, const float* __restrict__ bd1,
    const float* __restrict__ Wd2, const float* __restrict__ bd2,
    const float* __restrict__ lng, const float* __restrict__ lnb,
    const int* __restrict__ Kp, const int* __restrict__ candIdx,
    const float* __restrict__ candDist,
    const float* __restrict__ Vc, const float* __restrict__ S0,
    const unsigned short* __restrict__ Y,
    float* __restrict__ out) {

    __shared__ unsigned short sX[32][520];     // X tile bf16 (padded: 1040B rows, 16B-aligned)
    __shared__ float sS[32][116];              // raw scores vs all 7 cand x 8 h x 2 mats (112 cols)
    __shared__ unsigned short sVc[KM1][520];   // V rows bf16
    __shared__ float sW[32][8][6];             // biased scores -> softmax weights
    __shared__ float sBias[32][6][2][8];       // bias MLP partials (2 halves of hidden dim)
    __shared__ int   snbr[32][6];
    __shared__ float skd[32][6];
    __shared__ float srd[32];
    __shared__ float sE[32];
    __shared__ float sS0[112];

    int t = threadIdx.x;
    int b = blockIdx.x >> 5, rblk = blockIdx.x & 31;
    int row0 = b * CN + rblk * 32;   // global flat row
    int K = *Kp;

    // ---- phase A: staging
    for (int idx = t; idx < 32 * 128; idx += 256) {
        int r = idx >> 7, c4 = idx & 127;
        float4 xv = *(const float4*)(X + (size_t)(row0 + r) * CD + c4 * 4);
        us4 o; o.x = f2bf(xv.x); o.y = f2bf(xv.y); o.z = f2bf(xv.z); o.w = f2bf(xv.w);
        *(us4*)&sX[r][c4 * 4] = o;
    }
    for (int idx = t; idx < KM1 * 128; idx += 256) {
        int m = idx >> 7, c4 = idx & 127;
        float4 vv = *(const float4*)(Vc + ((size_t)(b * KM1 + m)) * CD + c4 * 4);
        us4 o; o.x = f2bf(vv.x); o.y = f2bf(vv.y); o.z = f2bf(vv.z); o.w = f2bf(vv.w);
        *(us4*)&sVc[m][c4 * 4] = o;
    }
    if (t < 112) sS0[t] = S0[b * 112 + t];
    if (t < 32) {
        int i = rblk * 32 + t;
        sE[t]  = mask[b * CN + i];
        srd[t] = dist[b * CN + i];
        int cnt = 0;
        for (int m = 0; m <= K && cnt < K; m++) {
            int c = candIdx[b * KM1 + m];
            if (c != i) { snbr[t][cnt] = m; skd[t][cnt] = candDist[b * KM1 + m]; cnt++; }
        }
    }
    __syncthreads();

    // ---- phase B1: score MFMA  S[r][n] = X_r . Y_n  (K=512)
    {
        int w = t >> 6, lane = t & 63, lr = lane & 15, kg = lane >> 4;
        f32x4 acc00 = {0.f, 0.f, 0.f, 0.f}, acc10 = acc00, acc01 = acc00, acc11 = acc00;
        bool has2 = (w < 3);
        const unsigned short* Yb = Y + (size_t)b * 112 * 512;
        const unsigned short* y0p = Yb + (size_t)(w * 16 + lr) * 512 + kg * 8;
        const unsigned short* y1p = Yb + (size_t)((w + 4) * 16 + lr) * 512 + kg * 8;
#pragma unroll
        for (int s = 0; s < 16; s++) {
            int k0 = s * 32 + kg * 8;
            bf8 a0 = *(const bf8*)&sX[lr][k0];
            bf8 a1 = *(const bf8*)&sX[16 + lr][k0];
            bf8 b0 = *(const bf8*)&y0p[s * 32];
            acc00 = __builtin_amdgcn_mfma_f32_16x16x32_bf16(a0, b0, acc00, 0, 0, 0);
            acc10 = __builtin_amdgcn_mfma_f32_16x16x32_bf16(a1, b0, acc10, 0, 0, 0);
            if (has2) {
                bf8 b1 = *(const bf8*)&y1p[s * 32];
                acc01 = __builtin_amdgcn_mfma_f32_16x16x32_bf16(a0, b1, acc01, 0, 0, 0);
                acc11 = __builtin_amdgcn_mfma_f32_16x16x32_bf16(a1, b1, acc11, 0, 0, 0);
            }
        }
        int n0 = w * 16 + lr;
#pragma unroll
        for (int q = 0; q < 4; q++) {
            sS[kg * 4 + q][n0]      = acc00[q];
            sS[16 + kg * 4 + q][n0] = acc10[q];
        }
        if (has2) {
            int n1 = (w + 4) * 16 + lr;
#pragma unroll
            for (int q = 0; q < 4; q++) {
                sS[kg * 4 + q][n1]      = acc01[q];
                sS[16 + kg * 4 + q][n1] = acc11[q];
            }
        }
    }
    // ---- phase B2: bias MLP (2 threads per (r,k) pair, split hidden dim)
    {
        int half = t & 1;
        int j0 = half * 64;
        for (int pid = t >> 1; pid < 32 * K; pid += 128) {
            int r = pid / K, k = pid - r * K;
            float qd = srd[r], kd = skd[r][k];
            float bacc[8];
#pragma unroll
            for (int h = 0; h < 8; h++) bacc[h] = 0.f;
            for (int j = j0; j < j0 + 64; j++) {
                float hid = fmaf(qd, Wd1[j], fmaf(kd, Wd1[128 + j], bd1[j]));
                hid = fmaxf(hid, 0.f);
                float4 wa = *(const float4*)(Wd2 + j * 8);
                float4 wb = *(const float4*)(Wd2 + j * 8 + 4);
                bacc[0] = fmaf(hid, wa.x, bacc[0]);
                bacc[1] = fmaf(hid, wa.y, bacc[1]);
                bacc[2] = fmaf(hid, wa.z, bacc[2]);
                bacc[3] = fmaf(hid, wa.w, bacc[3]);
                bacc[4] = fmaf(hid, wb.x, bacc[4]);
                bacc[5] = fmaf(hid, wb.y, bacc[5]);
                bacc[6] = fmaf(hid, wb.z, bacc[6]);
                bacc[7] = fmaf(hid, wb.w, bacc[7]);
            }
#pragma unroll
            for (int h = 0; h < 8; h++) sBias[r][k][half][h] = bacc[h];
        }
    }
    __syncthreads();

    // ---- phase C: blend ego/non-ego scores, multiply bias
    {
        int tot = 32 * 8 * K;
        for (int id = t; id < tot; id += 256) {
            int k = id % K; int rh = id / K; int r = rh >> 3, h = rh & 7;
            int m = snbr[r][k];
            float e = sE[r];
            float scq = sS[r][m * 8 + h]      + sS0[m * 8 + h];
            float sce = sS[r][56 + m * 8 + h] + sS0[56 + m * 8 + h];
            float sc = (1.f - e) * scq + e * sce;
            float bias = sBias[r][k][0][h] + sBias[r][k][1][h] + bd2[h];
            sW[r][h][k] = sc * 0.125f * bias;
        }
    }
    __syncthreads();

    // ---- phase D: softmax over k (256 tasks exactly)
    {
        int r = t >> 3, h = t & 7;
        float mx = -3.4e38f;
        for (int k = 0; k < K; k++) mx = fmaxf(mx, sW[r][h][k]);
        float sum = 0.f;
        for (int k = 0; k < K; k++) {
            float w0 = __expf(sW[r][h][k] - mx);
            sW[r][h][k] = w0;
            sum += w0;
        }
        float inv = 1.f / sum;
        for (int k = 0; k < K; k++) sW[r][h][k] *= inv;
    }
    __syncthreads();

    // ---- phase E: PV + residual + LayerNorm (8 threads per row)
    {
        int r = t >> 3, tr = t & 7;
        const float* xrow = X + (size_t)(row0 + r) * CD;
        float4 vals[16];
        float sum = 0.f, sq = 0.f;
#pragma unroll
        for (int j = 0; j < 16; j++) {
            int d = tr * 4 + j * 32;
            int h = j >> 1;
            float ax = 0.f, ay = 0.f, az = 0.f, aw = 0.f;
            for (int k = 0; k < K; k++) {
                int m = snbr[r][k];
                float wgt = sW[r][h][k];
                us4 vv = *(const us4*)&sVc[m][d];
                ax = fmaf(wgt, bf2f(vv.x), ax);
                ay = fmaf(wgt, bf2f(vv.y), ay);
                az = fmaf(wgt, bf2f(vv.z), az);
                aw = fmaf(wgt, bf2f(vv.w), aw);
            }
            float4 xv = *(const float4*)(xrow + d);
            float4 v;
            v.x = xv.x + ax; v.y = xv.y + ay; v.z = xv.z + az; v.w = xv.w + aw;
            vals[j] = v;
            sum += v.x + v.y + v.z + v.w;
            sq = fmaf(v.x, v.x, sq); sq = fmaf(v.y, v.y, sq);
            sq = fmaf(v.z, v.z, sq); sq = fmaf(v.w, v.w, sq);
        }
        sum += __shfl_xor(sum, 1); sq += __shfl_xor(sq, 1);
        sum += __shfl_xor(sum, 2); sq += __shfl_xor(sq, 2);
        sum += __shfl_xor(sum, 4); sq += __shfl_xor(sq, 4);
        float mu  = sum * (1.f / 512.f);
        float var = sq * (1.f / 512.f) - mu * mu;
        float inv = rsqrtf(var + 1e-5f);
        float* orow = out + (size_t)(row0 + r) * CD;
#pragma unroll
        for (int j = 0; j < 16; j++) {
            int d = tr * 4 + j * 32;
            float4 g  = *(const float4*)(lng + d);
            float4 bb = *(const float4*)(lnb + d);
            float4 v = vals[j];
            float4 o;
            o.x = (v.x - mu) * inv * g.x + bb.x;
            o.y = (v.y - mu) * inv * g.y + bb.y;
            o.z = (v.z - mu) * inv * g.z + bb.z;
            o.w = (v.w - mu) * inv * g.w + bb.w;
            *(float4*)(orow + d) = o;
        }
    }
}

// ---------------------------------------------------------------------------
extern "C" void kernel_launch(void* const* d_in, const int* in_sizes, int n_in,
                              void* d_out, int out_size, void* d_ws, size_t ws_size,
                              hipStream_t stream) {
    (void)in_sizes; (void)n_in; (void)out_size; (void)ws_size;
    const float* X     = (const float*)d_in[0];
    const float* dist  = (const float*)d_in[1];
    const float* mask  = (const float*)d_in[2];
    const float* speed = (const float*)d_in[3];
    const float* Wq    = (const float*)d_in[4];
    const float* bq    = (const float*)d_in[5];
    const float* Wk    = (const float*)d_in[6];
    const float* bk    = (const float*)d_in[7];
    const float* Wv    = (const float*)d_in[8];
    const float* bv    = (const float*)d_in[9];
    const float* Weq   = (const float*)d_in[10];
    const float* beq   = (const float*)d_in[11];
    const float* Wd1   = (const float*)d_in[16];
    const float* bd1   = (const float*)d_in[17];
    const float* Wd2   = (const float*)d_in[18];
    const float* bd2   = (const float*)d_in[19];
    const float* lng   = (const float*)d_in[20];
    const float* lnb   = (const float*)d_in[21];
    float* out = (float*)d_out;

    char* ws = (char*)d_ws;
    int*   Kp       = (int*)(ws);
    int*   candIdx  = (int*)(ws + 256);
    float* candDist = (float*)(ws + 1024);
    float* S0       = (float*)(ws + 2048);                 // 16*2*7*8*4 = 7168 B
    float* Kc       = (float*)(ws + 16384);                // 229376 B
    float* Vc       = (float*)(ws + 245760);               // 229376 B
    unsigned short* Y = (unsigned short*)(ws + 475136);    // 16*112*512*2 = 1835008 B

    k_computeK<<<1, 256, 0, stream>>>(dist, speed, Kp);
    k_top7<<<CB, 64, 0, stream>>>(dist, candIdx, candDist);
    k_candkv<<<dim3(CB, 4), 256, 0, stream>>>(X, Wk, bk, Wv, bv, candIdx, Kc, Vc);
    k_Y<<<dim3(CB * 8, 2), 256, 0, stream>>>(Wq, bq, Weq, beq, Kc, S0, Y);
    k_attn<<<CB * 32, 256, 0, stream>>>(X, dist, mask, Wd1, bd1, Wd2, bd2, lng, lnb,
                                        Kp, candIdx, candDist, Vc, S0, Y, out);
}

// Round 4
// 121.367 us; speedup vs baseline: 3.3068x; 1.5137x over previous
//
#include <hip/hip_runtime.h>
#include <math.h>

constexpr int CB  = 16;
constexpr int CN  = 1024;
constexpr int CD  = 512;
constexpr int KM1 = 7;      // K_MAX + 1 candidate slots per batch

typedef __attribute__((ext_vector_type(8))) short bf8;
typedef __attribute__((ext_vector_type(4))) float f32x4;
typedef __attribute__((ext_vector_type(4))) unsigned short us4;

__device__ inline float bf2f(unsigned short u) {
    union { unsigned int i; float f; } v; v.i = ((unsigned)u) << 16; return v.f;
}
__device__ inline unsigned short f2bf(float f) {
    union { unsigned int i; float f; } v; v.f = f;
    unsigned r = v.i + 0x7FFFu + ((v.i >> 16) & 1u);
    return (unsigned short)(r >> 16);
}
__device__ inline bf8 pack8(float4 x, float4 y) {
    bf8 r;
    r[0] = (short)f2bf(x.x); r[1] = (short)f2bf(x.y);
    r[2] = (short)f2bf(x.z); r[3] = (short)f2bf(x.w);
    r[4] = (short)f2bf(y.x); r[5] = (short)f2bf(y.y);
    r[6] = (short)f2bf(y.z); r[7] = (short)f2bf(y.w);
    return r;
}

// ---------------------------------------------------------------------------
// Kernel A: compute K (scalar) from ego_speed / ego_distance
// ---------------------------------------------------------------------------
__global__ void k_computeK(const float* __restrict__ dist,
                           const float* __restrict__ speed,
                           int* __restrict__ Kout) {
    __shared__ int red[256];
    int t = threadIdx.x;
    int cnt = 0;
    for (int i = t; i < CB * CN; i += 256) cnt += (dist[i] < 20.0f) ? 1 : 0;
    red[t] = cnt;
    __syncthreads();
    for (int s = 128; s > 0; s >>= 1) {
        if (t < s) red[t] += red[t + s];
        __syncthreads();
    }
    if (t == 0) {
        float ss = 0.f;
        for (int i = 0; i < CB; i++) ss += speed[i];
        int K = 4;
        if (ss / (float)CB > 15.0f) K = (K + 1 > 6) ? 6 : K + 1;
        float density = (float)red[0] / (float)(CB * CN);
        if (density > 0.5f) K = (K + 1 > 6) ? 6 : K + 1;
        if (K > CN - 1) K = CN - 1;
        if (K < 0) K = 0;
        *Kout = K;
    }
}

// ---------------------------------------------------------------------------
// Kernel B: per-batch top-7 smallest distances (indices + values)
// ---------------------------------------------------------------------------
__global__ void k_top7(const float* __restrict__ dist,
                       int* __restrict__ candIdx,
                       float* __restrict__ candDist) {
    int b = blockIdx.x;
    int lane = threadIdx.x;  // 64 threads
    float d7[KM1];
    int   i7[KM1];
#pragma unroll
    for (int j = 0; j < KM1; j++) { d7[j] = 3.4e38f; i7[j] = -1; }
    for (int i = lane; i < CN; i += 64) {
        float d = dist[b * CN + i];
        if (d < d7[KM1 - 1]) {
            int p = KM1 - 1;
            while (p > 0 && d7[p - 1] > d) {
                d7[p] = d7[p - 1]; i7[p] = i7[p - 1]; p--;
            }
            d7[p] = d; i7[p] = i;
        }
    }
    __shared__ float sd[64 * KM1];
    __shared__ int   si[64 * KM1];
    for (int j = 0; j < KM1; j++) { sd[lane * KM1 + j] = d7[j]; si[lane * KM1 + j] = i7[j]; }
    __syncthreads();
    if (lane == 0) {
        float m7[KM1];
        int   mi[KM1];
        for (int j = 0; j < KM1; j++) { m7[j] = 3.4e38f; mi[j] = -1; }
        for (int e = 0; e < 64 * KM1; e++) {
            float d = sd[e];
            if (d < m7[KM1 - 1]) {
                int ii = si[e];
                int p = KM1 - 1;
                while (p > 0 && m7[p - 1] > d) {
                    m7[p] = m7[p - 1]; mi[p] = mi[p - 1]; p--;
                }
                m7[p] = d; mi[p] = ii;
            }
        }
        for (int j = 0; j < KM1; j++) {
            candIdx[b * KM1 + j]  = mi[j];
            candDist[b * KM1 + j] = m7[j];
        }
    }
}

// ---------------------------------------------------------------------------
// Kernel C (MFMA): K/V projections of the 7 candidate rows per batch.
//   Per block (b, ny, mat): out[m][c] = sum_k Xc[m][k] * W[k][c] + bias[c]
//   for c in [ny*64, ny*64+64), via 16x16x32 bf16 MFMA.
//   A = Xc [7(pad16) x 512] bf16 in LDS; B-frags from strided W loads (L2-hot).
// ---------------------------------------------------------------------------
__global__ __launch_bounds__(256) void k_candkv(
    const float* __restrict__ X,
    const float* __restrict__ Wk, const float* __restrict__ bk,
    const float* __restrict__ Wv, const float* __restrict__ bv,
    const int* __restrict__ candIdx,
    float* __restrict__ Kc, float* __restrict__ Vc) {
    int b   = blockIdx.x;
    int ny  = blockIdx.y;
    int mat = blockIdx.z;
    const float* W    = mat ? Wv : Wk;
    const float* bias = mat ? bv : bk;
    float*       Out  = mat ? Vc : Kc;

    __shared__ unsigned short sA[16][520];
    int t = threadIdx.x;
    for (int i = t; i < 16 * 128; i += 256) {
        int m = i >> 7, c4 = i & 127;
        float4 xv = {0.f, 0.f, 0.f, 0.f};
        if (m < KM1)
            xv = *(const float4*)(X + (size_t)(b * CN + candIdx[b * KM1 + m]) * CD + c4 * 4);
        us4 o; o.x = f2bf(xv.x); o.y = f2bf(xv.y); o.z = f2bf(xv.z); o.w = f2bf(xv.w);
        *(us4*)&sA[m][c4 * 4] = o;
    }
    __syncthreads();

    int w = t >> 6, lane = t & 63, lr = lane & 15, kg = lane >> 4;
    int c = ny * 64 + w * 16 + lr;
    const float* wbase = W + (size_t)(kg * 8) * CD + c;
    f32x4 acc = {0.f, 0.f, 0.f, 0.f};
#pragma unroll
    for (int s = 0; s < 16; s++) {
        const float* wp = wbase + (size_t)s * 32 * CD;
        bf8 bfr;
        bfr[0] = (short)f2bf(wp[0 * CD]);
        bfr[1] = (short)f2bf(wp[1 * CD]);
        bfr[2] = (short)f2bf(wp[2 * CD]);
        bfr[3] = (short)f2bf(wp[3 * CD]);
        bfr[4] = (short)f2bf(wp[4 * CD]);
        bfr[5] = (short)f2bf(wp[5 * CD]);
        bfr[6] = (short)f2bf(wp[6 * CD]);
        bfr[7] = (short)f2bf(wp[7 * CD]);
        bf8 a = *(const bf8*)&sA[lr][s * 32 + kg * 8];
        acc = __builtin_amdgcn_mfma_f32_16x16x32_bf16(a, bfr, acc, 0, 0, 0);
    }
    float bv_ = bias[c];
#pragma unroll
    for (int q = 0; q < 4; q++) {
        int m = kg * 4 + q;
        if (m < KM1)
            Out[(size_t)(b * KM1 + m) * CD + c] = acc[q] + bv_;
    }
}

// ---------------------------------------------------------------------------
// Kernel Y (MFMA): per block (b,h,half):
//   Y[b][mat*56 + m*8 + h][k] = sum_{c in head h} W[k][c] * Kc[b][m][c]
//   S0[b][mat][m][h] = sum_{c in head} bias[c]*Kc[b][m][c]  (half==0 only)
// ---------------------------------------------------------------------------
__global__ __launch_bounds__(256) void k_Y(
    const float* __restrict__ Wq, const float* __restrict__ bq,
    const float* __restrict__ Weq, const float* __restrict__ beq,
    const float* __restrict__ Kc, float* __restrict__ S0,
    unsigned short* __restrict__ Y) {
    int b = blockIdx.x >> 3, h = blockIdx.x & 7;
    int half = blockIdx.y;
    __shared__ unsigned short sA[16][64];
    __shared__ float sKf[KM1][64];
    int t = threadIdx.x;
    for (int i = t; i < 16 * 64; i += 256) {
        int m = i >> 6, c = i & 63;
        float v = (m < KM1) ? Kc[((size_t)(b * KM1 + m)) * CD + h * 64 + c] : 0.f;
        sA[m][c] = f2bf(v);
        if (m < KM1) sKf[m][c] = v;
    }
    __syncthreads();
    if (half == 0 && t < 14) {
        int mat = t / 7, m = t % 7;
        const float* bias = mat ? beq : bq;
        float s = 0.f;
        for (int c = 0; c < 64; c++) s = fmaf(bias[h * 64 + c], sKf[m][c], s);
        S0[((b * 2 + mat) * KM1 + m) * 8 + h] = s;
    }
    int w = t >> 6, lane = t & 63, lr = lane & 15, kg = lane >> 4;
    bf8 a0 = *(const bf8*)&sA[lr][kg * 8];
    bf8 a1 = *(const bf8*)&sA[lr][32 + kg * 8];
#pragma unroll
    for (int mat = 0; mat < 2; mat++) {
        const float* W = mat ? Weq : Wq;
        unsigned short* Yb = Y + ((size_t)(b * 112) + mat * 56) * 512;
#pragma unroll
        for (int nt = 0; nt < 4; nt++) {
            int n0 = (half * 16 + w * 4 + nt) * 16;   // k_out tile base
            const float* wp = W + (size_t)(n0 + lr) * CD + h * 64 + kg * 8;
            float4 f0 = *(const float4*)(wp);
            float4 f1 = *(const float4*)(wp + 4);
            float4 f2 = *(const float4*)(wp + 32);
            float4 f3 = *(const float4*)(wp + 36);
            f32x4 acc = {0.f, 0.f, 0.f, 0.f};
            acc = __builtin_amdgcn_mfma_f32_16x16x32_bf16(a0, pack8(f0, f1), acc, 0, 0, 0);
            acc = __builtin_amdgcn_mfma_f32_16x16x32_bf16(a1, pack8(f2, f3), acc, 0, 0, 0);
            int k_out = n0 + lr;
#pragma unroll
            for (int q = 0; q < 4; q++) {
                int m = kg * 4 + q;   // A row
                if (m < KM1)
                    Yb[(size_t)(m * 8 + h) * 512 + k_out] = f2bf(acc[q]);
            }
        }
    }
}

// ---------------------------------------------------------------------------
// Kernel attn: fused scores (MFMA vs Y) + bias MLP + softmax + PV + residual + LN
// Block = 32 rows of one batch; 256 threads; grid = 16*32 = 512.
// ---------------------------------------------------------------------------
__global__ __launch_bounds__(256) void k_attn(
    const float* __restrict__ X, const float* __restrict__ dist,
    const float* __restrict__ mask,
    const float* __restrict__ Wd1, const float* __restrict__ bd1,
    const float* __restrict__ Wd2, const float* __restrict__ bd2,
    const float* __restrict__ lng, const float* __restrict__ lnb,
    const int* __restrict__ Kp, const int* __restrict__ candIdx,
    const float* __restrict__ candDist,
    const float* __restrict__ Vc, const float* __restrict__ S0,
    const unsigned short* __restrict__ Y,
    float* __restrict__ out) {

    __shared__ unsigned short sX[32][520];     // X tile bf16 (padded: 1040B rows, 16B-aligned)
    __shared__ float sS[32][116];              // raw scores vs all 7 cand x 8 h x 2 mats (112 cols)
    __shared__ unsigned short sVc[KM1][520];   // V rows bf16
    __shared__ float sW[32][8][6];             // biased scores -> softmax weights
    __shared__ float sBias[32][6][2][8];       // bias MLP partials (2 halves of hidden dim)
    __shared__ int   snbr[32][6];
    __shared__ float skd[32][6];
    __shared__ float srd[32];
    __shared__ float sE[32];
    __shared__ float sS0[112];

    int t = threadIdx.x;
    int b = blockIdx.x >> 5, rblk = blockIdx.x & 31;
    int row0 = b * CN + rblk * 32;   // global flat row
    int K = *Kp;

    // ---- phase A: staging
    for (int idx = t; idx < 32 * 128; idx += 256) {
        int r = idx >> 7, c4 = idx & 127;
        float4 xv = *(const float4*)(X + (size_t)(row0 + r) * CD + c4 * 4);
        us4 o; o.x = f2bf(xv.x); o.y = f2bf(xv.y); o.z = f2bf(xv.z); o.w = f2bf(xv.w);
        *(us4*)&sX[r][c4 * 4] = o;
    }
    for (int idx = t; idx < KM1 * 128; idx += 256) {
        int m = idx >> 7, c4 = idx & 127;
        float4 vv = *(const float4*)(Vc + ((size_t)(b * KM1 + m)) * CD + c4 * 4);
        us4 o; o.x = f2bf(vv.x); o.y = f2bf(vv.y); o.z = f2bf(vv.z); o.w = f2bf(vv.w);
        *(us4*)&sVc[m][c4 * 4] = o;
    }
    if (t < 112) sS0[t] = S0[b * 112 + t];
    if (t < 32) {
        int i = rblk * 32 + t;
        sE[t]  = mask[b * CN + i];
        srd[t] = dist[b * CN + i];
        int cnt = 0;
        for (int m = 0; m <= K && cnt < K; m++) {
            int c = candIdx[b * KM1 + m];
            if (c != i) { snbr[t][cnt] = m; skd[t][cnt] = candDist[b * KM1 + m]; cnt++; }
        }
    }
    __syncthreads();

    // ---- phase B1: score MFMA  S[r][n] = X_r . Y_n  (K=512)
    {
        int w = t >> 6, lane = t & 63, lr = lane & 15, kg = lane >> 4;
        f32x4 acc00 = {0.f, 0.f, 0.f, 0.f}, acc10 = acc00, acc01 = acc00, acc11 = acc00;
        bool has2 = (w < 3);
        const unsigned short* Yb = Y + (size_t)b * 112 * 512;
        const unsigned short* y0p = Yb + (size_t)(w * 16 + lr) * 512 + kg * 8;
        const unsigned short* y1p = Yb + (size_t)((w + 4) * 16 + lr) * 512 + kg * 8;
#pragma unroll
        for (int s = 0; s < 16; s++) {
            int k0 = s * 32 + kg * 8;
            bf8 a0 = *(const bf8*)&sX[lr][k0];
            bf8 a1 = *(const bf8*)&sX[16 + lr][k0];
            bf8 b0 = *(const bf8*)&y0p[s * 32];
            acc00 = __builtin_amdgcn_mfma_f32_16x16x32_bf16(a0, b0, acc00, 0, 0, 0);
            acc10 = __builtin_amdgcn_mfma_f32_16x16x32_bf16(a1, b0, acc10, 0, 0, 0);
            if (has2) {
                bf8 b1 = *(const bf8*)&y1p[s * 32];
                acc01 = __builtin_amdgcn_mfma_f32_16x16x32_bf16(a0, b1, acc01, 0, 0, 0);
                acc11 = __builtin_amdgcn_mfma_f32_16x16x32_bf16(a1, b1, acc11, 0, 0, 0);
            }
        }
        int n0 = w * 16 + lr;
#pragma unroll
        for (int q = 0; q < 4; q++) {
            sS[kg * 4 + q][n0]      = acc00[q];
            sS[16 + kg * 4 + q][n0] = acc10[q];
        }
        if (has2) {
            int n1 = (w + 4) * 16 + lr;
#pragma unroll
            for (int q = 0; q < 4; q++) {
                sS[kg * 4 + q][n1]      = acc01[q];
                sS[16 + kg * 4 + q][n1] = acc11[q];
            }
        }
    }
    // ---- phase B2: bias MLP (2 threads per (r,k) pair, split hidden dim)
    {
        int half = t & 1;
        int j0 = half * 64;
        for (int pid = t >> 1; pid < 32 * K; pid += 128) {
            int r = pid / K, k = pid - r * K;
            float qd = srd[r], kd = skd[r][k];
            float bacc[8];
#pragma unroll
            for (int h = 0; h < 8; h++) bacc[h] = 0.f;
            for (int j = j0; j < j0 + 64; j++) {
                float hid = fmaf(qd, Wd1[j], fmaf(kd, Wd1[128 + j], bd1[j]));
                hid = fmaxf(hid, 0.f);
                float4 wa = *(const float4*)(Wd2 + j * 8);
                float4 wb = *(const float4*)(Wd2 + j * 8 + 4);
                bacc[0] = fmaf(hid, wa.x, bacc[0]);
                bacc[1] = fmaf(hid, wa.y, bacc[1]);
                bacc[2] = fmaf(hid, wa.z, bacc[2]);
                bacc[3] = fmaf(hid, wa.w, bacc[3]);
                bacc[4] = fmaf(hid, wb.x, bacc[4]);
                bacc[5] = fmaf(hid, wb.y, bacc[5]);
                bacc[6] = fmaf(hid, wb.z, bacc[6]);
                bacc[7] = fmaf(hid, wb.w, bacc[7]);
            }
#pragma unroll
            for (int h = 0; h < 8; h++) sBias[r][k][half][h] = bacc[h];
        }
    }
    __syncthreads();

    // ---- phase C: blend ego/non-ego scores, multiply bias
    {
        int tot = 32 * 8 * K;
        for (int id = t; id < tot; id += 256) {
            int k = id % K; int rh = id / K; int r = rh >> 3, h = rh & 7;
            int m = snbr[r][k];
            float e = sE[r];
            float scq = sS[r][m * 8 + h]      + sS0[m * 8 + h];
            float sce = sS[r][56 + m * 8 + h] + sS0[56 + m * 8 + h];
            float sc = (1.f - e) * scq + e * sce;
            float bias = sBias[r][k][0][h] + sBias[r][k][1][h] + bd2[h];
            sW[r][h][k] = sc * 0.125f * bias;
        }
    }
    __syncthreads();

    // ---- phase D: softmax over k (256 tasks exactly)
    {
        int r = t >> 3, h = t & 7;
        float mx = -3.4e38f;
        for (int k = 0; k < K; k++) mx = fmaxf(mx, sW[r][h][k]);
        float sum = 0.f;
        for (int k = 0; k < K; k++) {
            float w0 = __expf(sW[r][h][k] - mx);
            sW[r][h][k] = w0;
            sum += w0;
        }
        float inv = 1.f / sum;
        for (int k = 0; k < K; k++) sW[r][h][k] *= inv;
    }
    __syncthreads();

    // ---- phase E: PV + residual + LayerNorm (8 threads per row)
    {
        int r = t >> 3, tr = t & 7;
        const float* xrow = X + (size_t)(row0 + r) * CD;
        float4 vals[16];
        float sum = 0.f, sq = 0.f;
#pragma unroll
        for (int j = 0; j < 16; j++) {
            int d = tr * 4 + j * 32;
            int h = j >> 1;
            float ax = 0.f, ay = 0.f, az = 0.f, aw = 0.f;
            for (int k = 0; k < K; k++) {
                int m = snbr[r][k];
                float wgt = sW[r][h][k];
                us4 vv = *(const us4*)&sVc[m][d];
                ax = fmaf(wgt, bf2f(vv.x), ax);
                ay = fmaf(wgt, bf2f(vv.y), ay);
                az = fmaf(wgt, bf2f(vv.z), az);
                aw = fmaf(wgt, bf2f(vv.w), aw);
            }
            float4 xv = *(const float4*)(xrow + d);
            float4 v;
            v.x = xv.x + ax; v.y = xv.y + ay; v.z = xv.z + az; v.w = xv.w + aw;
            vals[j] = v;
            sum += v.x + v.y + v.z + v.w;
            sq = fmaf(v.x, v.x, sq); sq = fmaf(v.y, v.y, sq);
            sq = fmaf(v.z, v.z, sq); sq = fmaf(v.w, v.w, sq);
        }
        sum += __shfl_xor(sum, 1); sq += __shfl_xor(sq, 1);
        sum += __shfl_xor(sum, 2); sq += __shfl_xor(sq, 2);
        sum += __shfl_xor(sum, 4); sq += __shfl_xor(sq, 4);
        float mu  = sum * (1.f / 512.f);
        float var = sq * (1.f / 512.f) - mu * mu;
        float inv = rsqrtf(var + 1e-5f);
        float* orow = out + (size_t)(row0 + r) * CD;
#pragma unroll
        for (int j = 0; j < 16; j++) {
            int d = tr * 4 + j * 32;
            float4 g  = *(const float4*)(lng + d);
            float4 bb = *(const float4*)(lnb + d);
            float4 v = vals[j];
            float4 o;
            o.x = (v.x - mu) * inv * g.x + bb.x;
            o.y = (v.y - mu) * inv * g.y + bb.y;
            o.z = (v.z - mu) * inv * g.z + bb.z;
            o.w = (v.w - mu) * inv * g.w + bb.w;
            *(float4*)(orow + d) = o;
        }
    }
}

// ---------------------------------------------------------------------------
extern "C" void kernel_launch(void* const* d_in, const int* in_sizes, int n_in,
                              void* d_out, int out_size, void* d_ws, size_t ws_size,
                              hipStream_t stream) {
    (void)in_sizes; (void)n_in; (void)out_size; (void)ws_size;
    const float* X     = (const float*)d_in[0];
    const float* dist  = (const float*)d_in[1];
    const float* mask  = (const float*)d_in[2];
    const float* speed = (const float*)d_in[3];
    const float* Wq    = (const float*)d_in[4];
    const float* bq    = (const float*)d_in[5];
    const float* Wk    = (const float*)d_in[6];
    const float* bk    = (const float*)d_in[7];
    const float* Wv    = (const float*)d_in[8];
    const float* bv    = (const float*)d_in[9];
    const float* Weq   = (const float*)d_in[10];
    const float* beq   = (const float*)d_in[11];
    const float* Wd1   = (const float*)d_in[16];
    const float* bd1   = (const float*)d_in[17];
    const float* Wd2   = (const float*)d_in[18];
    const float* bd2   = (const float*)d_in[19];
    const float* lng   = (const float*)d_in[20];
    const float* lnb   = (const float*)d_in[21];
    float* out = (float*)d_out;

    char* ws = (char*)d_ws;
    int*   Kp       = (int*)(ws);
    int*   candIdx  = (int*)(ws + 256);
    float* candDist = (float*)(ws + 1024);
    float* S0       = (float*)(ws + 2048);                 // 16*2*7*8*4 = 7168 B
    float* Kc       = (float*)(ws + 16384);                // 229376 B
    float* Vc       = (float*)(ws + 245760);               // 229376 B
    unsigned short* Y = (unsigned short*)(ws + 475136);    // 16*112*512*2 = 1835008 B

    k_computeK<<<1, 256, 0, stream>>>(dist, speed, Kp);
    k_top7<<<CB, 64, 0, stream>>>(dist, candIdx, candDist);
    k_candkv<<<dim3(CB, 8, 2), 256, 0, stream>>>(X, Wk, bk, Wv, bv, candIdx, Kc, Vc);
    k_Y<<<dim3(CB * 8, 2), 256, 0, stream>>>(Wq, bq, Weq, beq, Kc, S0, Y);
    k_attn<<<CB * 32, 256, 0, stream>>>(X, dist, mask, Wd1, bd1, Wd2, bd2, lng, lnb,
                                        Kp, candIdx, candDist, Vc, S0, Y, out);
}